// Round 3
// baseline (405.494 us; speedup 1.0000x reference)
//
#include <hip/hip_runtime.h>
#include <hip/hip_bf16.h>

typedef __bf16 bf16x8 __attribute__((ext_vector_type(8)));
typedef float  f32x4  __attribute__((ext_vector_type(4)));
typedef unsigned short u16x8 __attribute__((ext_vector_type(8)));
typedef unsigned short USHORT;

__device__ __forceinline__ USHORT f2bf(float f) {
    unsigned u = __float_as_uint(f);
    u += 0x7fffu + ((u >> 16) & 1u);
    return (USHORT)(u >> 16);
}

__device__ __forceinline__ unsigned pack2bf(float x, float y) {
    union { __hip_bfloat162 h; unsigned u; } c;
    c.h = __float22bfloat162_rn(float2{x, y});
    return c.u;
}

__device__ __forceinline__ f32x4 fz4() { f32x4 z = {0.f, 0.f, 0.f, 0.f}; return z; }

__device__ __forceinline__ bf16x8 ldbf8(const USHORT* p) { return *(const bf16x8*)p; }

__device__ __forceinline__ f32x4 mfma16(bf16x8 a, bf16x8 b, f32x4 c) {
    return __builtin_amdgcn_mfma_f32_16x16x32_bf16(a, b, c, 0, 0, 0);
}

// async global->LDS, 16B per lane; LDS dest is wave-uniform base + lane*16
__device__ __forceinline__ void gload_lds16(const void* g, void* s) {
    __builtin_amdgcn_global_load_lds(
        (const __attribute__((address_space(1))) unsigned int*)g,
        (__attribute__((address_space(3))) unsigned int*)s, 16, 0, 0);
}

// ---------------- merged prep: X cvt + W transposes + ctx zero -----------------
// blocks [0,2048): X cvt. [2048,3328): Wqkv^T. [3328,4352): Wout^T.
// [4352,6400): zero ctx (16.8 MB fp32).
__global__ __launch_bounds__(256) void prep_kernel(const float* __restrict__ X,
                                                   const float* __restrict__ Wqkv,
                                                   const float* __restrict__ Wout,
                                                   USHORT* __restrict__ Xb,
                                                   USHORT* __restrict__ Wt1,
                                                   USHORT* __restrict__ Wt3,
                                                   float* __restrict__ ctx) {
    int bid = blockIdx.x;
    if (bid < 2048) {
        int base = (bid * 256 + threadIdx.x) * 8;
        float4 a = *(const float4*)(X + base);
        float4 b = *(const float4*)(X + base + 4);
        u16x8 o;
        o[0] = f2bf(a.x); o[1] = f2bf(a.y); o[2] = f2bf(a.z); o[3] = f2bf(a.w);
        o[4] = f2bf(b.x); o[5] = f2bf(b.y); o[6] = f2bf(b.z); o[7] = f2bf(b.w);
        *(u16x8*)(Xb + base) = o;
    } else if (bid < 3328) {
        int t = (bid - 2048) * 256 + threadIdx.x;   // 640x512
        int k = t & 511, n = t >> 9;
        Wt1[t] = f2bf(Wqkv[(size_t)k * 1536 + n]);
    } else if (bid < 4352) {
        int t = (bid - 3328) * 256 + threadIdx.x;   // 512x512
        int k = t & 511, n = t >> 9;
        Wt3[t] = f2bf(Wout[(size_t)k * 512 + n]);
    } else {
        int base = ((bid - 4352) * 256 + threadIdx.x) * 8;
        float4 z = {0.f, 0.f, 0.f, 0.f};
        *(float4*)(ctx + base) = z;
        *(float4*)(ctx + base + 4) = z;
    }
}

// ---------------- fp32 -> bf16 convert (8 elems/thread) ------------------------
__global__ __launch_bounds__(256) void cvt_f32_bf16(const float* __restrict__ src,
                                                    USHORT* __restrict__ dst) {
    int base = (blockIdx.x * 256 + threadIdx.x) * 8;
    float4 a = *(const float4*)(src + base);
    float4 b = *(const float4*)(src + base + 4);
    u16x8 o;
    o[0] = f2bf(a.x); o[1] = f2bf(a.y); o[2] = f2bf(a.z); o[3] = f2bf(a.w);
    o[4] = f2bf(b.x); o[5] = f2bf(b.y); o[6] = f2bf(b.z); o[7] = f2bf(b.w);
    *(u16x8*)(dst + base) = o;
}

// ---------------- m97-style bf16 GEMM: C = A(MxK) * Bt(NxK)^T -------------------
template <bool BF16OUT>
__global__ __launch_bounds__(256) void gemm_bt(const USHORT* __restrict__ A,
                                               const USHORT* __restrict__ Bt,
                                               void* __restrict__ Cv,
                                               int M, int N, int K) {
    __shared__ __align__(16) USHORT Asm[128 * 32];
    __shared__ __align__(16) USHORT Bsm[128 * 32];
    const int tid = threadIdx.x;
    const int wv = tid >> 6, ln = tid & 63;
    const int l16 = ln & 15, quad = ln >> 4;
    const int m0 = blockIdx.x * 128, n0 = blockIdx.y * 128;
    const int wm = (wv >> 1) * 64, wn = (wv & 1) * 64;

    f32x4 acc[4][4];
#pragma unroll
    for (int i = 0; i < 4; ++i)
#pragma unroll
        for (int j = 0; j < 4; ++j) acc[i][j] = fz4();

    const int kTiles = K >> 5;
    for (int kt = 0; kt < kTiles; ++kt) {
        __syncthreads();
#pragma unroll
        for (int i = 0; i < 2; ++i) {
            int cb = wv * 128 + i * 64;
            int c = cb + ln;
            gload_lds16(A + (size_t)(m0 + (c >> 2)) * K + kt * 32 + (c & 3) * 8,
                        &Asm[cb * 8]);
            gload_lds16(Bt + (size_t)(n0 + (c >> 2)) * K + kt * 32 + (c & 3) * 8,
                        &Bsm[cb * 8]);
        }
        __syncthreads();

        bf16x8 af[4], bfr[4];
#pragma unroll
        for (int i = 0; i < 4; ++i)
            af[i] = ldbf8(&Asm[(wm + i * 16 + l16) * 32 + quad * 8]);
#pragma unroll
        for (int j = 0; j < 4; ++j)
            bfr[j] = ldbf8(&Bsm[(wn + j * 16 + l16) * 32 + quad * 8]);
#pragma unroll
        for (int i = 0; i < 4; ++i)
#pragma unroll
            for (int j = 0; j < 4; ++j)
                acc[i][j] = mfma16(af[i], bfr[j], acc[i][j]);
    }

#pragma unroll
    for (int i = 0; i < 4; ++i)
#pragma unroll
        for (int j = 0; j < 4; ++j)
#pragma unroll
            for (int r = 0; r < 4; ++r) {
                size_t row = m0 + wm + i * 16 + quad * 4 + r;
                size_t col = n0 + wn + j * 16 + l16;
                if (BF16OUT)
                    ((USHORT*)Cv)[row * N + col] = f2bf(acc[i][j][r]);
                else
                    ((float*)Cv)[row * N + col] = acc[i][j][r];
            }
}

// ---------------- V transpose: Vt[((b*8+h)*64+d)*1024+k] = P[(b*1024+k)*640+(h+2)*64+d]
__global__ __launch_bounds__(256) void transpose_v(const USHORT* __restrict__ P,
                                                   USHORT* __restrict__ Vt) {
    __shared__ __align__(16) USHORT T[64][72];
    const int t = threadIdx.x;
    const int k0 = blockIdx.x * 64;
    const int hh = blockIdx.y;
    const int b = blockIdx.z;
#pragma unroll
    for (int i = 0; i < 2; ++i) {
        int c = i * 256 + t;
        int kk = c >> 3, d8 = (c & 7) * 8;
        u16x8 v = *(const u16x8*)(P + (size_t)((b << 10) + k0 + kk) * 640 +
                                  (hh + 2) * 64 + d8);
        *(u16x8*)&T[kk][d8] = v;
    }
    __syncthreads();
#pragma unroll
    for (int i = 0; i < 2; ++i) {
        int d = (t >> 3) + i * 32;
        int kk0 = (t & 7) * 8;
        u16x8 v;
#pragma unroll
        for (int j = 0; j < 8; ++j) v[j] = T[kk0 + j][d];
        *(u16x8*)(Vt + (size_t)(((b << 3) + hh) * 64 + d) * 1024 + k0 + kk0) = v;
    }
}

// ---------------- fused attention v3: staged, 4-wave WGs ------------------------
// grid (qb=16, h=8, kc=4) = 512 WGs x 256 thr; wave w owns q-rows qb*64+w*16.
// Per 32-key step: stage K (8b x 32k x 64d, 32KB) + V^T (8b x 64d x 32k, 32KB)
// into LDS via global_load_lds, XOR-chunk-swizzled in the SOURCE address so
// the b128 fragment reads are conflict-light (staging dest must be lane-
// contiguous). Scores computed TRANSPOSED (A=K, B=Q) so the attn C->B-operand
// transform is 2x ds_write_b64 + 1x ds_read_b128 through a wave-private
// double buffer, and the O^T epilogue atomics are 4-contiguous floats.
// Softmax is over the BATCH axis: per-lane across the 8 in-register batches.
__global__ __launch_bounds__(256, 2) void attn_kernel(const USHORT* __restrict__ P,
                                                      const USHORT* __restrict__ Vt,
                                                      float* __restrict__ ctx) {
    __shared__ __align__(16) USHORT Ksm[8][32][64];   // 32 KB
    __shared__ __align__(16) USHORT Vsm[8][64][32];   // 32 KB
    __shared__ __align__(16) USHORT Sw[4][2][16][40]; // 10 KB, wave-private dbuf

    const int qb = blockIdx.x, h = blockIdx.y, kc = blockIdx.z;
    const int tid = threadIdx.x;
    const int wv = tid >> 6, ln = tid & 63;
    const int l16 = ln & 15, quad = ln >> 4;
    const int q0 = qb * 64 + wv * 16;

    // staging source coords (fixed per thread)
    const int rowK = wv * 8 + (ln >> 3);            // 0..31
    const int cgK  = (ln & 7) ^ (rowK & 7);
    const int dV   = wv * 16 + (ln >> 2);           // 0..63
    const int cgV  = (ln & 3) ^ (dV & 3);

    // Q fragments (B-operand: n=q=l16, k=d=quad*8+j), kept in registers
    bf16x8 qf[8][2];
#pragma unroll
    for (int b = 0; b < 8; ++b)
#pragma unroll
        for (int ks = 0; ks < 2; ++ks)
            qf[b][ks] = ldbf8(P + (size_t)((b << 10) + q0 + l16) * 640 + h * 64 +
                              ks * 32 + quad * 8);

    f32x4 oacc[8][4];
#pragma unroll
    for (int b = 0; b < 8; ++b)
#pragma unroll
        for (int nt = 0; nt < 4; ++nt) oacc[b][nt] = fz4();

    for (int it = 0; it < 8; ++it) {
        const int k0 = kc * 256 + it * 32;

        __syncthreads();  // prev-step LDS reads done before overwrite
#pragma unroll
        for (int b = 0; b < 8; ++b) {
            gload_lds16(P + (size_t)((b << 10) + k0 + rowK) * 640 + (h + 1) * 64 + cgK * 8,
                        &Ksm[b][wv * 8][0]);
            gload_lds16(Vt + (size_t)(((b << 3) + h) * 64 + dV) * 1024 + k0 + cgV * 8,
                        &Vsm[b][wv * 16][0]);
        }
        __syncthreads();  // drains vmcnt for global_load_lds

        // ---- scores, transposed: sacc[b][kt] = K_tile * Q^T  (m=key, n=q) ----
        f32x4 sacc[8][2];
#pragma unroll
        for (int b = 0; b < 8; ++b) { sacc[b][0] = fz4(); sacc[b][1] = fz4(); }
#pragma unroll
        for (int ks = 0; ks < 2; ++ks)
#pragma unroll
            for (int kt = 0; kt < 2; ++kt) {
                bf16x8 kf[8];
#pragma unroll
                for (int b = 0; b < 8; ++b)
                    kf[b] = ldbf8(&Ksm[b][kt * 16 + l16][(((ks << 2) + quad) ^ (l16 & 7)) * 8]);
#pragma unroll
                for (int b = 0; b < 8; ++b)
                    sacc[b][kt] = mfma16(kf[b], qf[b][ks], sacc[b][kt]);
            }

        // ---- softmax over batch axis (per-lane); exp2 in place ----
        f32x4 Zv[2] = {fz4(), fz4()};
#pragma unroll
        for (int b = 0; b < 8; ++b)
#pragma unroll
            for (int kt = 0; kt < 2; ++kt) {
#pragma unroll
                for (int r = 0; r < 4; ++r)
                    sacc[b][kt][r] =
                        __builtin_amdgcn_exp2f(sacc[b][kt][r] * 0.1803368801f);
                Zv[kt] += sacc[b][kt];
            }
        f32x4 inv[2];
#pragma unroll
        for (int kt = 0; kt < 2; ++kt)
#pragma unroll
            for (int r = 0; r < 4; ++r)
                inv[kt][r] = __builtin_amdgcn_rcpf(Zv[kt][r]);

        // ---- per-batch: pack attn -> wave-private LDS -> B-frag -> PV ----
#pragma unroll
        for (int b = 0; b < 8; ++b) {
            USHORT* swp = &Sw[wv][b & 1][0][0];
#pragma unroll
            for (int kt = 0; kt < 2; ++kt) {
                f32x4 p = sacc[b][kt] * inv[kt];
                uint2 pk;
                pk.x = pack2bf(p[0], p[1]);
                pk.y = pack2bf(p[2], p[3]);
                *(uint2*)(swp + l16 * 40 + kt * 16 + quad * 4) = pk;
            }
            bf16x8 atf = ldbf8(swp + l16 * 40 + quad * 8);
            bf16x8 vf[4];
#pragma unroll
            for (int nt = 0; nt < 4; ++nt)
                vf[nt] = ldbf8(&Vsm[b][nt * 16 + l16][(quad ^ (l16 & 3)) * 8]);
#pragma unroll
            for (int nt = 0; nt < 4; ++nt)
                oacc[b][nt] = mfma16(vf[nt], atf, oacc[b][nt]);
        }
    }

    // O^T epilogue: lane holds 4 contiguous d per (b,nt) -> coalesced atomics
#pragma unroll
    for (int b = 0; b < 8; ++b)
#pragma unroll
        for (int nt = 0; nt < 4; ++nt) {
            float* base = ctx + (size_t)((b << 10) + q0 + l16) * 512 +
                          h * 64 + nt * 16 + quad * 4;
#pragma unroll
            for (int r = 0; r < 4; ++r)
                unsafeAtomicAdd(base + r, oacc[b][nt][r]);
        }
}

extern "C" void kernel_launch(void* const* d_in, const int* in_sizes, int n_in,
                              void* d_out, int out_size, void* d_ws, size_t ws_size,
                              hipStream_t stream) {
    const float* X = (const float*)d_in[0];     // (8,1024,512)
    const float* Wqkv = (const float*)d_in[1];  // (512,1536) — only cols 0..639 used
    const float* Wout = (const float*)d_in[2];  // (512,512)
    float* out = (float*)d_out;                 // (8,1024,512) fp32

    char* w = (char*)d_ws;
    USHORT* Xb  = (USHORT*)(w);              //  8,388,608 B (reused as CtxB later)
    USHORT* Wt1 = (USHORT*)(w + 8388608);    //    655,360 B  (640x512)
    USHORT* Wt3 = (USHORT*)(w + 9043968);    //    524,288 B  (512x512)
    USHORT* P   = (USHORT*)(w + 9568256);    // 10,485,760 B  (8192x640 bf16)
    USHORT* Vt  = (USHORT*)(w + 20054016);   //  8,388,608 B  (8x8x64x1024 bf16)
    float*  ctx = (float*)(w + 28442624);    // 16,777,216 B  (8192x512 fp32) end=45.2MB
    USHORT* CtxB = Xb;                       // Xb dead after GEMM1

    prep_kernel<<<6400, 256, 0, stream>>>(X, Wqkv, Wout, Xb, Wt1, Wt3, ctx);
    // P = Xb @ Wqkv[:, :640]
    gemm_bt<true><<<dim3(64, 5), 256, 0, stream>>>(Xb, Wt1, (void*)P, 8192, 640, 512);
    transpose_v<<<dim3(16, 8, 8), 256, 0, stream>>>(P, Vt);
    attn_kernel<<<dim3(16, 8, 4), 256, 0, stream>>>(P, Vt, ctx);
    cvt_f32_bf16<<<2048, 256, 0, stream>>>(ctx, CtxB);
    // out = ctx @ W_out
    gemm_bt<false><<<dim3(64, 4), 256, 0, stream>>>(CtxB, Wt3, (void*)out, 8192, 512, 512);
}

// Round 4
// 391.311 us; speedup vs baseline: 1.0362x; 1.0362x over previous
//
#include <hip/hip_runtime.h>
#include <hip/hip_bf16.h>

typedef __bf16 bf16x8 __attribute__((ext_vector_type(8)));
typedef float  f32x4  __attribute__((ext_vector_type(4)));
typedef unsigned short u16x8 __attribute__((ext_vector_type(8)));
typedef unsigned short USHORT;

__device__ __forceinline__ USHORT f2bf(float f) {
    unsigned u = __float_as_uint(f);
    u += 0x7fffu + ((u >> 16) & 1u);
    return (USHORT)(u >> 16);
}

__device__ __forceinline__ unsigned pack2bf(float x, float y) {
    union { __hip_bfloat162 h; unsigned u; } c;
    c.h = __float22bfloat162_rn(float2{x, y});
    return c.u;
}

__device__ __forceinline__ f32x4 fz4() { f32x4 z = {0.f, 0.f, 0.f, 0.f}; return z; }

__device__ __forceinline__ bf16x8 ldbf8(const USHORT* p) { return *(const bf16x8*)p; }

__device__ __forceinline__ f32x4 mfma16(bf16x8 a, bf16x8 b, f32x4 c) {
    return __builtin_amdgcn_mfma_f32_16x16x32_bf16(a, b, c, 0, 0, 0);
}

// async global->LDS, 16B per lane; LDS dest is wave-uniform base + lane*16
__device__ __forceinline__ void gload_lds16(const void* g, void* s) {
    __builtin_amdgcn_global_load_lds(
        (const __attribute__((address_space(1))) unsigned int*)g,
        (__attribute__((address_space(3))) unsigned int*)s, 16, 0, 0);
}

// ---------------- merged prep: X cvt + W transposes + ctx zero -----------------
__global__ __launch_bounds__(256) void prep_kernel(const float* __restrict__ X,
                                                   const float* __restrict__ Wqkv,
                                                   const float* __restrict__ Wout,
                                                   USHORT* __restrict__ Xb,
                                                   USHORT* __restrict__ Wt1,
                                                   USHORT* __restrict__ Wt3,
                                                   float* __restrict__ ctx) {
    int bid = blockIdx.x;
    if (bid < 2048) {
        int base = (bid * 256 + threadIdx.x) * 8;
        float4 a = *(const float4*)(X + base);
        float4 b = *(const float4*)(X + base + 4);
        u16x8 o;
        o[0] = f2bf(a.x); o[1] = f2bf(a.y); o[2] = f2bf(a.z); o[3] = f2bf(a.w);
        o[4] = f2bf(b.x); o[5] = f2bf(b.y); o[6] = f2bf(b.z); o[7] = f2bf(b.w);
        *(u16x8*)(Xb + base) = o;
    } else if (bid < 3328) {
        int t = (bid - 2048) * 256 + threadIdx.x;   // 640x512
        int k = t & 511, n = t >> 9;
        Wt1[t] = f2bf(Wqkv[(size_t)k * 1536 + n]);
    } else if (bid < 4352) {
        int t = (bid - 3328) * 256 + threadIdx.x;   // 512x512
        int k = t & 511, n = t >> 9;
        Wt3[t] = f2bf(Wout[(size_t)k * 512 + n]);
    } else {
        int base = ((bid - 4352) * 256 + threadIdx.x) * 8;
        float4 z = {0.f, 0.f, 0.f, 0.f};
        *(float4*)(ctx + base) = z;
        *(float4*)(ctx + base + 4) = z;
    }
}

// ---------------- fp32 -> bf16 convert (8 elems/thread) ------------------------
__global__ __launch_bounds__(256) void cvt_f32_bf16(const float* __restrict__ src,
                                                    USHORT* __restrict__ dst) {
    int base = (blockIdx.x * 256 + threadIdx.x) * 8;
    float4 a = *(const float4*)(src + base);
    float4 b = *(const float4*)(src + base + 4);
    u16x8 o;
    o[0] = f2bf(a.x); o[1] = f2bf(a.y); o[2] = f2bf(a.z); o[3] = f2bf(a.w);
    o[4] = f2bf(b.x); o[5] = f2bf(b.y); o[6] = f2bf(b.z); o[7] = f2bf(b.w);
    *(u16x8*)(dst + base) = o;
}

// ---------------- m97-style bf16 GEMM: C = A(MxK) * Bt(NxK)^T -------------------
template <bool BF16OUT>
__global__ __launch_bounds__(256) void gemm_bt(const USHORT* __restrict__ A,
                                               const USHORT* __restrict__ Bt,
                                               void* __restrict__ Cv,
                                               int M, int N, int K) {
    __shared__ __align__(16) USHORT Asm[128 * 32];
    __shared__ __align__(16) USHORT Bsm[128 * 32];
    const int tid = threadIdx.x;
    const int wv = tid >> 6, ln = tid & 63;
    const int l16 = ln & 15, quad = ln >> 4;
    const int m0 = blockIdx.x * 128, n0 = blockIdx.y * 128;
    const int wm = (wv >> 1) * 64, wn = (wv & 1) * 64;

    f32x4 acc[4][4];
#pragma unroll
    for (int i = 0; i < 4; ++i)
#pragma unroll
        for (int j = 0; j < 4; ++j) acc[i][j] = fz4();

    const int kTiles = K >> 5;
    for (int kt = 0; kt < kTiles; ++kt) {
        __syncthreads();
#pragma unroll
        for (int i = 0; i < 2; ++i) {
            int cb = wv * 128 + i * 64;
            int c = cb + ln;
            gload_lds16(A + (size_t)(m0 + (c >> 2)) * K + kt * 32 + (c & 3) * 8,
                        &Asm[cb * 8]);
            gload_lds16(Bt + (size_t)(n0 + (c >> 2)) * K + kt * 32 + (c & 3) * 8,
                        &Bsm[cb * 8]);
        }
        __syncthreads();

        bf16x8 af[4], bfr[4];
#pragma unroll
        for (int i = 0; i < 4; ++i)
            af[i] = ldbf8(&Asm[(wm + i * 16 + l16) * 32 + quad * 8]);
#pragma unroll
        for (int j = 0; j < 4; ++j)
            bfr[j] = ldbf8(&Bsm[(wn + j * 16 + l16) * 32 + quad * 8]);
#pragma unroll
        for (int i = 0; i < 4; ++i)
#pragma unroll
            for (int j = 0; j < 4; ++j)
                acc[i][j] = mfma16(af[i], bfr[j], acc[i][j]);
    }

#pragma unroll
    for (int i = 0; i < 4; ++i)
#pragma unroll
        for (int j = 0; j < 4; ++j)
#pragma unroll
            for (int r = 0; r < 4; ++r) {
                size_t row = m0 + wm + i * 16 + quad * 4 + r;
                size_t col = n0 + wn + j * 16 + l16;
                if (BF16OUT)
                    ((USHORT*)Cv)[row * N + col] = f2bf(acc[i][j][r]);
                else
                    ((float*)Cv)[row * N + col] = acc[i][j][r];
            }
}

// ---------------- V transpose: Vt[((b*8+h)*64+d)*1024+k] = P[(b*1024+k)*640+(h+2)*64+d]
__global__ __launch_bounds__(256) void transpose_v(const USHORT* __restrict__ P,
                                                   USHORT* __restrict__ Vt) {
    __shared__ __align__(16) USHORT T[64][72];
    const int t = threadIdx.x;
    const int k0 = blockIdx.x * 64;
    const int hh = blockIdx.y;
    const int b = blockIdx.z;
#pragma unroll
    for (int i = 0; i < 2; ++i) {
        int c = i * 256 + t;
        int kk = c >> 3, d8 = (c & 7) * 8;
        u16x8 v = *(const u16x8*)(P + (size_t)((b << 10) + k0 + kk) * 640 +
                                  (hh + 2) * 64 + d8);
        *(u16x8*)&T[kk][d8] = v;
    }
    __syncthreads();
#pragma unroll
    for (int i = 0; i < 2; ++i) {
        int d = (t >> 3) + i * 32;
        int kk0 = (t & 7) * 8;
        u16x8 v;
#pragma unroll
        for (int j = 0; j < 8; ++j) v[j] = T[kk0 + j][d];
        *(u16x8*)(Vt + (size_t)(((b << 3) + hh) * 64 + d) * 1024 + k0 + kk0) = v;
    }
}

// ---------------- fused attention v4: staged, 4-wave WGs, spill-free ------------
// Same structure as v3 (staged K/V in LDS, transposed scores, packed attn
// transform, O^T contiguous atomics) with the register budget fixed:
//  - staging addresses live in 4 rolled-loop pointers (was 16 unrolled addrs)
//  - K fragments loaded from LDS one at a time, feeding MFMA directly
// Live set ~170 regs (qf 32 + sacc 64 + oacc 32 AGPR + misc) < 256 @ 2 w/SIMD.
__global__ __launch_bounds__(256, 2) void attn_kernel(const USHORT* __restrict__ P,
                                                      const USHORT* __restrict__ Vt,
                                                      float* __restrict__ ctx) {
    __shared__ __align__(16) USHORT Ksm[8][32][64];   // 32 KB
    __shared__ __align__(16) USHORT Vsm[8][64][32];   // 32 KB
    __shared__ __align__(16) USHORT Sw[4][2][16][40]; // 10 KB, wave-private dbuf

    const int qb = blockIdx.x, h = blockIdx.y, kc = blockIdx.z;
    const int tid = threadIdx.x;
    const int wv = tid >> 6, ln = tid & 63;
    const int l16 = ln & 15, quad = ln >> 4;
    const int q0 = qb * 64 + wv * 16;

    // staging source coords (fixed per thread)
    const int rowK = wv * 8 + (ln >> 3);            // 0..31
    const int cgK  = (ln & 7) ^ (rowK & 7);
    const int dV   = wv * 16 + (ln >> 2);           // 0..63
    const int cgV  = (ln & 3) ^ (dV & 3);

    // Q fragments (B-operand: n=q=l16, k=d=quad*8+j), kept in registers
    bf16x8 qf[8][2];
#pragma unroll
    for (int b = 0; b < 8; ++b)
#pragma unroll
        for (int ks = 0; ks < 2; ++ks)
            qf[b][ks] = ldbf8(P + (size_t)((b << 10) + q0 + l16) * 640 + h * 64 +
                              ks * 32 + quad * 8);

    f32x4 oacc[8][4];
#pragma unroll
    for (int b = 0; b < 8; ++b)
#pragma unroll
        for (int nt = 0; nt < 4; ++nt) oacc[b][nt] = fz4();

    for (int it = 0; it < 8; ++it) {
        const int k0 = kc * 256 + it * 32;

        __syncthreads();  // prev-step LDS reads done before overwrite
        {
            const USHORT* pK = P + (size_t)(k0 + rowK) * 640 + (h + 1) * 64 + cgK * 8;
            const USHORT* pV = Vt + (size_t)(h * 64 + dV) * 1024 + k0 + cgV * 8;
            USHORT* sK = &Ksm[0][wv * 8][0];
            USHORT* sV = &Vsm[0][wv * 16][0];
#pragma unroll 1
            for (int b = 0; b < 8; ++b) {
                gload_lds16(pK, sK);
                gload_lds16(pV, sV);
                pK += 1024 * 640;       // batch stride in P
                pV += 8 * 64 * 1024;    // batch stride in Vt
                sK += 32 * 64;
                sV += 64 * 32;
            }
        }
        __syncthreads();  // drains vmcnt for global_load_lds

        // ---- scores, transposed: sacc[b][kt] = K_tile * Q^T  (m=key, n=q) ----
        f32x4 sacc[8][2];
#pragma unroll
        for (int b = 0; b < 8; ++b) { sacc[b][0] = fz4(); sacc[b][1] = fz4(); }
#pragma unroll
        for (int b = 0; b < 8; ++b)
#pragma unroll
            for (int kt = 0; kt < 2; ++kt)
#pragma unroll
                for (int ks = 0; ks < 2; ++ks) {
                    bf16x8 kf = ldbf8(
                        &Ksm[b][kt * 16 + l16][(((ks << 2) + quad) ^ (l16 & 7)) * 8]);
                    sacc[b][kt] = mfma16(kf, qf[b][ks], sacc[b][kt]);
                }

        // ---- softmax over batch axis (per-lane); exp2 in place ----
        f32x4 Zv[2] = {fz4(), fz4()};
#pragma unroll
        for (int b = 0; b < 8; ++b)
#pragma unroll
            for (int kt = 0; kt < 2; ++kt) {
#pragma unroll
                for (int r = 0; r < 4; ++r)
                    sacc[b][kt][r] =
                        __builtin_amdgcn_exp2f(sacc[b][kt][r] * 0.1803368801f);
                Zv[kt] += sacc[b][kt];
            }
        f32x4 inv[2];
#pragma unroll
        for (int kt = 0; kt < 2; ++kt)
#pragma unroll
            for (int r = 0; r < 4; ++r)
                inv[kt][r] = __builtin_amdgcn_rcpf(Zv[kt][r]);

        // ---- per-batch: pack attn -> wave-private LDS -> B-frag -> PV ----
#pragma unroll
        for (int b = 0; b < 8; ++b) {
            USHORT* swp = &Sw[wv][b & 1][0][0];
#pragma unroll
            for (int kt = 0; kt < 2; ++kt) {
                f32x4 p = sacc[b][kt] * inv[kt];
                uint2 pk;
                pk.x = pack2bf(p[0], p[1]);
                pk.y = pack2bf(p[2], p[3]);
                *(uint2*)(swp + l16 * 40 + kt * 16 + quad * 4) = pk;
            }
            bf16x8 atf = ldbf8(swp + l16 * 40 + quad * 8);
#pragma unroll
            for (int nt = 0; nt < 4; ++nt) {
                bf16x8 vf = ldbf8(&Vsm[b][nt * 16 + l16][(quad ^ (l16 & 3)) * 8]);
                oacc[b][nt] = mfma16(vf, atf, oacc[b][nt]);
            }
        }
    }

    // O^T epilogue: lane holds 4 contiguous d per (b,nt) -> coalesced atomics
#pragma unroll
    for (int b = 0; b < 8; ++b)
#pragma unroll
        for (int nt = 0; nt < 4; ++nt) {
            float* base = ctx + (size_t)((b << 10) + q0 + l16) * 512 +
                          h * 64 + nt * 16 + quad * 4;
#pragma unroll
            for (int r = 0; r < 4; ++r)
                unsafeAtomicAdd(base + r, oacc[b][nt][r]);
        }
}

extern "C" void kernel_launch(void* const* d_in, const int* in_sizes, int n_in,
                              void* d_out, int out_size, void* d_ws, size_t ws_size,
                              hipStream_t stream) {
    const float* X = (const float*)d_in[0];     // (8,1024,512)
    const float* Wqkv = (const float*)d_in[1];  // (512,1536) — only cols 0..639 used
    const float* Wout = (const float*)d_in[2];  // (512,512)
    float* out = (float*)d_out;                 // (8,1024,512) fp32

    char* w = (char*)d_ws;
    USHORT* Xb  = (USHORT*)(w);              //  8,388,608 B (reused as CtxB later)
    USHORT* Wt1 = (USHORT*)(w + 8388608);    //    655,360 B  (640x512)
    USHORT* Wt3 = (USHORT*)(w + 9043968);    //    524,288 B  (512x512)
    USHORT* P   = (USHORT*)(w + 9568256);    // 10,485,760 B  (8192x640 bf16)
    USHORT* Vt  = (USHORT*)(w + 20054016);   //  8,388,608 B  (8x8x64x1024 bf16)
    float*  ctx = (float*)(w + 28442624);    // 16,777,216 B  (8192x512 fp32) end=45.2MB
    USHORT* CtxB = Xb;                       // Xb dead after GEMM1

    prep_kernel<<<6400, 256, 0, stream>>>(X, Wqkv, Wout, Xb, Wt1, Wt3, ctx);
    // P = Xb @ Wqkv[:, :640]
    gemm_bt<true><<<dim3(64, 5), 256, 0, stream>>>(Xb, Wt1, (void*)P, 8192, 640, 512);
    transpose_v<<<dim3(16, 8, 8), 256, 0, stream>>>(P, Vt);
    attn_kernel<<<dim3(16, 8, 4), 256, 0, stream>>>(P, Vt, ctx);
    cvt_f32_bf16<<<2048, 256, 0, stream>>>(ctx, CtxB);
    // out = ctx @ W_out
    gemm_bt<false><<<dim3(64, 4), 256, 0, stream>>>(CtxB, Wt3, (void*)out, 8192, 512, 512);
}

// Round 5
// 365.702 us; speedup vs baseline: 1.1088x; 1.0700x over previous
//
#include <hip/hip_runtime.h>
#include <hip/hip_bf16.h>

typedef __bf16 bf16x8 __attribute__((ext_vector_type(8)));
typedef __bf16 bf16x4 __attribute__((ext_vector_type(4)));
typedef short  s16x4  __attribute__((ext_vector_type(4)));
typedef float  f32x4  __attribute__((ext_vector_type(4)));
typedef unsigned short u16x8 __attribute__((ext_vector_type(8)));
typedef unsigned short USHORT;

__device__ __forceinline__ USHORT f2bf(float f) {
    unsigned u = __float_as_uint(f);
    u += 0x7fffu + ((u >> 16) & 1u);
    return (USHORT)(u >> 16);
}

__device__ __forceinline__ unsigned pack2bf(float x, float y) {
    union { __hip_bfloat162 h; unsigned u; } c;
    c.h = __float22bfloat162_rn(float2{x, y});
    return c.u;
}

__device__ __forceinline__ f32x4 fz4() { f32x4 z = {0.f, 0.f, 0.f, 0.f}; return z; }

__device__ __forceinline__ bf16x8 ldbf8(const USHORT* p) { return *(const bf16x8*)p; }

__device__ __forceinline__ f32x4 mfma16(bf16x8 a, bf16x8 b, f32x4 c) {
    return __builtin_amdgcn_mfma_f32_16x16x32_bf16(a, b, c, 0, 0, 0);
}

// K=16 MFMA: A/B = 4 bf16 (2 VGPRs). B layout (n=l16, k=quad*4+j) matches the
// C/D layout of the score MFMA (col=l16, row=quad*4+r) -> direct register PV.
__device__ __forceinline__ f32x4 mfma16k16(bf16x4 a, bf16x4 b, f32x4 c) {
#if __has_builtin(__builtin_amdgcn_mfma_f32_16x16x16_bf16)
    return __builtin_amdgcn_mfma_f32_16x16x16_bf16(a, b, c, 0, 0, 0);
#else
    return __builtin_amdgcn_mfma_f32_16x16x16bf16_1k(
        __builtin_bit_cast(s16x4, a), __builtin_bit_cast(s16x4, b), c, 0, 0, 0);
#endif
}

// async global->LDS, 16B per lane; LDS dest is wave-uniform base + lane*16
__device__ __forceinline__ void gload_lds16(const void* g, void* s) {
    __builtin_amdgcn_global_load_lds(
        (const __attribute__((address_space(1))) unsigned int*)g,
        (__attribute__((address_space(3))) unsigned int*)s, 16, 0, 0);
}

// ---------------- merged prep: X cvt + W transposes + ctx zero -----------------
__global__ __launch_bounds__(256) void prep_kernel(const float* __restrict__ X,
                                                   const float* __restrict__ Wqkv,
                                                   const float* __restrict__ Wout,
                                                   USHORT* __restrict__ Xb,
                                                   USHORT* __restrict__ Wt1,
                                                   USHORT* __restrict__ Wt3,
                                                   float* __restrict__ ctx) {
    int bid = blockIdx.x;
    if (bid < 2048) {
        int base = (bid * 256 + threadIdx.x) * 8;
        float4 a = *(const float4*)(X + base);
        float4 b = *(const float4*)(X + base + 4);
        u16x8 o;
        o[0] = f2bf(a.x); o[1] = f2bf(a.y); o[2] = f2bf(a.z); o[3] = f2bf(a.w);
        o[4] = f2bf(b.x); o[5] = f2bf(b.y); o[6] = f2bf(b.z); o[7] = f2bf(b.w);
        *(u16x8*)(Xb + base) = o;
    } else if (bid < 3328) {
        int t = (bid - 2048) * 256 + threadIdx.x;   // 640x512
        int k = t & 511, n = t >> 9;
        Wt1[t] = f2bf(Wqkv[(size_t)k * 1536 + n]);
    } else if (bid < 4352) {
        int t = (bid - 3328) * 256 + threadIdx.x;   // 512x512
        int k = t & 511, n = t >> 9;
        Wt3[t] = f2bf(Wout[(size_t)k * 512 + n]);
    } else {
        int base = ((bid - 4352) * 256 + threadIdx.x) * 8;
        float4 z = {0.f, 0.f, 0.f, 0.f};
        *(float4*)(ctx + base) = z;
        *(float4*)(ctx + base + 4) = z;
    }
}

// ---------------- fp32 -> bf16 convert (8 elems/thread) ------------------------
__global__ __launch_bounds__(256) void cvt_f32_bf16(const float* __restrict__ src,
                                                    USHORT* __restrict__ dst) {
    int base = (blockIdx.x * 256 + threadIdx.x) * 8;
    float4 a = *(const float4*)(src + base);
    float4 b = *(const float4*)(src + base + 4);
    u16x8 o;
    o[0] = f2bf(a.x); o[1] = f2bf(a.y); o[2] = f2bf(a.z); o[3] = f2bf(a.w);
    o[4] = f2bf(b.x); o[5] = f2bf(b.y); o[6] = f2bf(b.z); o[7] = f2bf(b.w);
    *(u16x8*)(dst + base) = o;
}

// ---------------- m97-style bf16 GEMM: C = A(MxK) * Bt(NxK)^T -------------------
template <bool BF16OUT>
__global__ __launch_bounds__(256) void gemm_bt(const USHORT* __restrict__ A,
                                               const USHORT* __restrict__ Bt,
                                               void* __restrict__ Cv,
                                               int M, int N, int K) {
    __shared__ __align__(16) USHORT Asm[128 * 32];
    __shared__ __align__(16) USHORT Bsm[128 * 32];
    const int tid = threadIdx.x;
    const int wv = tid >> 6, ln = tid & 63;
    const int l16 = ln & 15, quad = ln >> 4;
    const int m0 = blockIdx.x * 128, n0 = blockIdx.y * 128;
    const int wm = (wv >> 1) * 64, wn = (wv & 1) * 64;

    f32x4 acc[4][4];
#pragma unroll
    for (int i = 0; i < 4; ++i)
#pragma unroll
        for (int j = 0; j < 4; ++j) acc[i][j] = fz4();

    const int kTiles = K >> 5;
    for (int kt = 0; kt < kTiles; ++kt) {
        __syncthreads();
#pragma unroll
        for (int i = 0; i < 2; ++i) {
            int cb = wv * 128 + i * 64;
            int c = cb + ln;
            gload_lds16(A + (size_t)(m0 + (c >> 2)) * K + kt * 32 + (c & 3) * 8,
                        &Asm[cb * 8]);
            gload_lds16(Bt + (size_t)(n0 + (c >> 2)) * K + kt * 32 + (c & 3) * 8,
                        &Bsm[cb * 8]);
        }
        __syncthreads();

        bf16x8 af[4], bfr[4];
#pragma unroll
        for (int i = 0; i < 4; ++i)
            af[i] = ldbf8(&Asm[(wm + i * 16 + l16) * 32 + quad * 8]);
#pragma unroll
        for (int j = 0; j < 4; ++j)
            bfr[j] = ldbf8(&Bsm[(wn + j * 16 + l16) * 32 + quad * 8]);
#pragma unroll
        for (int i = 0; i < 4; ++i)
#pragma unroll
            for (int j = 0; j < 4; ++j)
                acc[i][j] = mfma16(af[i], bfr[j], acc[i][j]);
    }

#pragma unroll
    for (int i = 0; i < 4; ++i)
#pragma unroll
        for (int j = 0; j < 4; ++j)
#pragma unroll
            for (int r = 0; r < 4; ++r) {
                size_t row = m0 + wm + i * 16 + quad * 4 + r;
                size_t col = n0 + wn + j * 16 + l16;
                if (BF16OUT)
                    ((USHORT*)Cv)[row * N + col] = f2bf(acc[i][j][r]);
                else
                    ((float*)Cv)[row * N + col] = acc[i][j][r];
            }
}

// ---------------- V transpose: Vt[((b*8+h)*64+d)*1024+k] = P[(b*1024+k)*640+(h+2)*64+d]
__global__ __launch_bounds__(256) void transpose_v(const USHORT* __restrict__ P,
                                                   USHORT* __restrict__ Vt) {
    __shared__ __align__(16) USHORT T[64][72];
    const int t = threadIdx.x;
    const int k0 = blockIdx.x * 64;
    const int hh = blockIdx.y;
    const int b = blockIdx.z;
#pragma unroll
    for (int i = 0; i < 2; ++i) {
        int c = i * 256 + t;
        int kk = c >> 3, d8 = (c & 7) * 8;
        u16x8 v = *(const u16x8*)(P + (size_t)((b << 10) + k0 + kk) * 640 +
                                  (hh + 2) * 64 + d8);
        *(u16x8*)&T[kk][d8] = v;
    }
    __syncthreads();
#pragma unroll
    for (int i = 0; i < 2; ++i) {
        int d = (t >> 3) + i * 32;
        int kk0 = (t & 7) * 8;
        u16x8 v;
#pragma unroll
        for (int j = 0; j < 8; ++j) v[j] = T[kk0 + j][d];
        *(u16x8*)(Vt + (size_t)(((b << 3) + hh) * 64 + d) * 1024 + k0 + kk0) = v;
    }
}

// ---------------- fused attention v5: register-direct PV ------------------------
// grid (qb=16, h=8, kc=4) = 512 WGs x 4 waves; wave owns 16 q-rows, all 8 b.
// Per 32-key step: stage K[8b][32k][64d] + V^T[8b][64d][32k] (64 KB) via
// global_load_lds (source-XOR-swizzled). Then TWO 16-key halves; per half:
//   scores S^T = K*Q^T via K=32 MFMAs  -> sacc[8] (C: col=q=l16, row=key=quad*4+r)
//   per-lane batch softmax (8 batches resident in the same lane)
//   PV via K=16 MFMAs: softmaxed sacc IS the B-operand (n=l16,k=quad*4+j) —
//   no LDS round-trip. A-operand = V^T rows (8B reads, double-XOR swizzle).
// VGPR demand ~120 (qf 64 + sacc 32 + transients) <= 128; oacc 128 in AGPR.
__global__ __launch_bounds__(256, 2) void attn_kernel(const USHORT* __restrict__ P,
                                                      const USHORT* __restrict__ Vt,
                                                      float* __restrict__ ctx) {
    __shared__ __align__(16) USHORT Ksm[8][32][64];   // 32 KB
    __shared__ __align__(16) USHORT Vsm[8][64][32];   // 32 KB

    const int qb = blockIdx.x, h = blockIdx.y, kc = blockIdx.z;
    const int tid = threadIdx.x;
    const int wv = tid >> 6, ln = tid & 63;
    const int l16 = ln & 15, quad = ln >> 4;
    const int q0 = qb * 64 + wv * 16;

    // staging source coords (fixed per thread)
    const int rowK = wv * 8 + (ln >> 3);                          // 0..31
    const int cgK  = (ln & 7) ^ (rowK & 7);
    const int dV   = wv * 16 + (ln >> 2);                         // 0..63
    const int cgV  = (ln & 3) ^ (dV & 3) ^ ((dV >> 2) & 3);       // double-XOR

    // Q fragments (B-operand K=32: n=q=l16, k=d=quad*8+j): 64 VGPRs
    bf16x8 qf[8][2];
#pragma unroll
    for (int b = 0; b < 8; ++b)
#pragma unroll
        for (int ks = 0; ks < 2; ++ks)
            qf[b][ks] = ldbf8(P + (size_t)((b << 10) + q0 + l16) * 640 + h * 64 +
                              ks * 32 + quad * 8);

    f32x4 oacc[8][4];
#pragma unroll
    for (int b = 0; b < 8; ++b)
#pragma unroll
        for (int nt = 0; nt < 4; ++nt) oacc[b][nt] = fz4();

    // PV V-read swizzle pieces (nt-independent)
    const int pvx = (l16 & 3) ^ ((l16 >> 2) & 3);
    const int pvh = (quad & 1) * 4;

    for (int it = 0; it < 8; ++it) {
        const int k0 = kc * 256 + it * 32;

        __syncthreads();  // prev-step LDS reads done before overwrite
        {
            const USHORT* pK = P + (size_t)(k0 + rowK) * 640 + (h + 1) * 64 + cgK * 8;
            const USHORT* pV = Vt + (size_t)(h * 64 + dV) * 1024 + k0 + cgV * 8;
            USHORT* sK = &Ksm[0][wv * 8][0];
            USHORT* sV = &Vsm[0][wv * 16][0];
#pragma unroll 1
            for (int b = 0; b < 8; ++b) {
                gload_lds16(pK, sK);
                gload_lds16(pV, sV);
                pK += 1024 * 640;       // batch stride in P
                pV += 8 * 64 * 1024;    // batch stride in Vt
                sK += 32 * 64;
                sV += 64 * 32;
            }
        }
        __syncthreads();  // drains vmcnt for global_load_lds

#pragma unroll 1
        for (int kt = 0; kt < 2; ++kt) {
            // ---- scores: S^T[key16][q16] per batch, K=32 MFMAs ----
            f32x4 sacc[8];
#pragma unroll
            for (int b = 0; b < 8; ++b) {
                bf16x8 kf0 = ldbf8(&Ksm[b][kt * 16 + l16][(quad ^ (l16 & 7)) * 8]);
                f32x4 s = mfma16(kf0, qf[b][0], fz4());
                bf16x8 kf1 = ldbf8(&Ksm[b][kt * 16 + l16][((4 + quad) ^ (l16 & 7)) * 8]);
                sacc[b] = mfma16(kf1, qf[b][1], s);
            }

            // ---- softmax over batch axis (per-lane); exp2 in place ----
            f32x4 Zv = fz4();
#pragma unroll
            for (int b = 0; b < 8; ++b) {
#pragma unroll
                for (int r = 0; r < 4; ++r)
                    sacc[b][r] = __builtin_amdgcn_exp2f(sacc[b][r] * 0.1803368801f);
                Zv += sacc[b];
            }
            f32x4 inv;
#pragma unroll
            for (int r = 0; r < 4; ++r) inv[r] = __builtin_amdgcn_rcpf(Zv[r]);

            // ---- PV: attn (registers, B-operand of K=16 MFMA) x V^T ----
            const int pvc = (kt * 2 + (quad >> 1)) ^ pvx;   // physical 16B chunk
#pragma unroll
            for (int b = 0; b < 8; ++b) {
                f32x4 p = sacc[b] * inv;
                union { unsigned u[2]; bf16x4 v; } at;
                at.u[0] = pack2bf(p[0], p[1]);
                at.u[1] = pack2bf(p[2], p[3]);
#pragma unroll
                for (int nt = 0; nt < 4; ++nt) {
                    bf16x4 vf = *(const bf16x4*)&Vsm[b][nt * 16 + l16][pvc * 8 + pvh];
                    oacc[b][nt] = mfma16k16(vf, at.v, oacc[b][nt]);
                }
            }
        }
    }

    // O^T epilogue: lane holds 4 contiguous d per (b,nt) -> coalesced atomics
#pragma unroll
    for (int b = 0; b < 8; ++b)
#pragma unroll
        for (int nt = 0; nt < 4; ++nt) {
            float* base = ctx + (size_t)((b << 10) + q0 + l16) * 512 +
                          h * 64 + nt * 16 + quad * 4;
#pragma unroll
            for (int r = 0; r < 4; ++r)
                unsafeAtomicAdd(base + r, oacc[b][nt][r]);
        }
}

extern "C" void kernel_launch(void* const* d_in, const int* in_sizes, int n_in,
                              void* d_out, int out_size, void* d_ws, size_t ws_size,
                              hipStream_t stream) {
    const float* X = (const float*)d_in[0];     // (8,1024,512)
    const float* Wqkv = (const float*)d_in[1];  // (512,1536) — only cols 0..639 used
    const float* Wout = (const float*)d_in[2];  // (512,512)
    float* out = (float*)d_out;                 // (8,1024,512) fp32

    char* w = (char*)d_ws;
    USHORT* Xb  = (USHORT*)(w);              //  8,388,608 B (reused as CtxB later)
    USHORT* Wt1 = (USHORT*)(w + 8388608);    //    655,360 B  (640x512)
    USHORT* Wt3 = (USHORT*)(w + 9043968);    //    524,288 B  (512x512)
    USHORT* P   = (USHORT*)(w + 9568256);    // 10,485,760 B  (8192x640 bf16)
    USHORT* Vt  = (USHORT*)(w + 20054016);   //  8,388,608 B  (8x8x64x1024 bf16)
    float*  ctx = (float*)(w + 28442624);    // 16,777,216 B  (8192x512 fp32) end=45.2MB
    USHORT* CtxB = Xb;                       // Xb dead after GEMM1

    prep_kernel<<<6400, 256, 0, stream>>>(X, Wqkv, Wout, Xb, Wt1, Wt3, ctx);
    // P = Xb @ Wqkv[:, :640]
    gemm_bt<true><<<dim3(64, 5), 256, 0, stream>>>(Xb, Wt1, (void*)P, 8192, 640, 512);
    transpose_v<<<dim3(16, 8, 8), 256, 0, stream>>>(P, Vt);
    attn_kernel<<<dim3(16, 8, 4), 256, 0, stream>>>(P, Vt, ctx);
    cvt_f32_bf16<<<2048, 256, 0, stream>>>(ctx, CtxB);
    // out = ctx @ W_out
    gemm_bt<false><<<dim3(64, 4), 256, 0, stream>>>(CtxB, Wt3, (void*)out, 8192, 512, 512);
}